// Round 16
// baseline (183.679 us; speedup 1.0000x reference)
//
#include <hip/hip_runtime.h>
#include <hip/hip_bf16.h>
#include <stdint.h>

typedef uint16_t u16;
typedef uint32_t u32;
typedef __attribute__((ext_vector_type(8))) short bv8;    // 8 x bf16 (i16 bits), 4 VGPR
typedef __attribute__((ext_vector_type(4))) float f32x4;
typedef __attribute__((ext_vector_type(16))) float f32x16;
typedef __attribute__((ext_vector_type(2))) u32 u32x2;

#define MFMA(a,b,c)   __builtin_amdgcn_mfma_f32_16x16x32_bf16((a),(b),(c),0,0,0)
#define MFMA32(a,b,c) __builtin_amdgcn_mfma_f32_32x32x16_bf16((a),(b),(c),0,0,0)

__device__ __forceinline__ float bf2f(u16 v){ u32 x=(u32)v<<16; float f; __builtin_memcpy(&f,&x,4); return f; }
__device__ __forceinline__ u16 f2bf(float f){ u32 x; __builtin_memcpy(&x,&f,4); x += 0x7fffu + ((x>>16)&1u); return (u16)(x>>16); }
__device__ __forceinline__ u32 cvtpk_bf16(float lo, float hi){
  u32 r; asm("v_cvt_pk_bf16_f32 %0, %1, %2" : "=v"(r) : "v"(lo), "v"(hi)); return r;
}
__device__ __forceinline__ float exp2_fast(float x){
  float r; asm("v_exp_f32 %0, %1" : "=v"(r) : "v"(x)); return r;
}
__device__ __forceinline__ float rcp_fast(float x){
  float r; asm("v_rcp_f32 %0, %1" : "=v"(r) : "v"(x)); return r;
}

__device__ __forceinline__ void gl_lds16(const u16* g, u16* l){
  __builtin_amdgcn_global_load_lds((const __attribute__((address_space(1))) u32*)g,
                                   (__attribute__((address_space(3))) u32*)l, 16, 0, 0);
}

// fused fp32 -> bf16 convert of x / w_qkv / w_proj into contiguous ws region.
__global__ __launch_bounds__(256) void cvt3(const float* __restrict__ x, const float* __restrict__ wq,
                                            const float* __restrict__ wp, u16* __restrict__ dst){
  const long NA = 1048576, NB = 393216, NC = 131072;   // n8 per source
  long i = (long)blockIdx.x*256 + threadIdx.x;
  long stride = (long)gridDim.x*256;
  for(; i < NA+NB+NC; i += stride){
    const float* s;
    if(i < NA)            s = x  + i*8;
    else if(i < NA+NB)    s = wq + (i-NA)*8;
    else                  s = wp + (i-NA-NB)*8;
    f32x4 a = *(const f32x4*)(s);
    f32x4 b = *(const f32x4*)(s + 4);
    bv8 o;
    #pragma unroll
    for(int j=0;j<4;j++) o[j]   = (short)f2bf(a[j]);
    #pragma unroll
    for(int j=0;j<4;j++) o[4+j] = (short)f2bf(b[j]);
    *(bv8*)(dst + i*8) = o;
  }
}

// ---------------------------------------------------------------------------
// C[m,n] = sum_k A[m,k] * B[n,k]   (A: MxK bf16 row-major, B: NxK bf16)
// 128x128 tile, BK=64, 4 waves, global_load_lds w/ pre-swizzled src.
// MODE 1: fp32 out. MODE 2: bf16 out + fused RMSNorm+RoPE on q/k cols.
// ---------------------------------------------------------------------------
template<int MODE>
__global__ __launch_bounds__(256,2) void gemm_bt(const u16* __restrict__ A, const u16* __restrict__ B,
                                                 void* __restrict__ Cv, int M, int N, int K,
                                                 const float* __restrict__ cosT,
                                                 const float* __restrict__ sinT,
                                                 const float* __restrict__ qw,
                                                 const float* __restrict__ kw){
  __shared__ __align__(16) u16 As[128*64];
  __shared__ __align__(16) u16 Bs[128*64];
  int nwg = gridDim.x;
  int wg  = (int)blockIdx.x;
  wg = (wg & 7)*(nwg>>3) + (wg>>3);          // XCD swizzle (nwg % 8 == 0)
  int nn = N>>7;
  int tm = wg/nn, tn = wg - tm*nn;
  int rowbase = tm<<7, colbase = tn<<7;
  int t = threadIdx.x, lane = t&63, w = t>>6;
  int g = lane>>4, q16 = lane&15;
  int wr = w>>1, wc = w&1;

  f32x4 z = {0.f,0.f,0.f,0.f};
  f32x4 acc[4][4];
  #pragma unroll
  for(int i=0;i<4;i++)
    #pragma unroll
    for(int j=0;j<4;j++) acc[i][j]=z;

  for(int k0=0;k0<K;k0+=64){
    __syncthreads();
    #pragma unroll
    for(int i=0;i<4;i++){
      int s = ((w<<2)+i)*64 + lane;
      int row = s>>3;
      int ksl = (s&7) ^ (row&7);
      gl_lds16(A + (size_t)(rowbase+row)*K + k0 + ksl*8, (u16*)As + ((w<<2)+i)*512);
      gl_lds16(B + (size_t)(colbase+row)*K + k0 + ksl*8, (u16*)Bs + ((w<<2)+i)*512);
    }
    __syncthreads();
    #pragma unroll
    for(int eks=0;eks<2;eks++){
      bv8 af[4], bfr[4];
      #pragma unroll
      for(int mi=0;mi<4;mi++){
        int row = (wr<<6)+(mi<<4)+q16;
        af[mi] = *(const bv8*)(As + row*64 + ((((eks<<2)|g) ^ (row&7))<<3));
      }
      #pragma unroll
      for(int ni=0;ni<4;ni++){
        int row = (wc<<6)+(ni<<4)+q16;
        bfr[ni] = *(const bv8*)(Bs + row*64 + ((((eks<<2)|g) ^ (row&7))<<3));
      }
      #pragma unroll
      for(int mi=0;mi<4;mi++)
        #pragma unroll
        for(int ni=0;ni<4;ni++)
          acc[mi][ni] = MFMA(af[mi], bfr[ni], acc[mi][ni]);
    }
  }

  if(MODE==2 && colbase < 2048){
    // fused RMSNorm + RoPE (+ q pre-scale 0.125*log2e) on this q/k head
    int s = colbase>>10;                       // 0=q, 1=k
    const float* wsel = s ? kw : qw;
    int ch = colbase + (wc<<6);
    float qsc = s ? 1.0f : 0.1803368801111437f;
    float wv[4];
    #pragma unroll
    for(int ni=0;ni<4;ni++) wv[ni] = wsel[(ni<<4)|q16];
    #pragma unroll
    for(int mi=0;mi<4;mi++){
      #pragma unroll
      for(int r=0;r<4;r++){
        int row = rowbase + (wr<<6)+(mi<<4)+(g<<2)+r;
        int l = row & 1023;
        float y[4];
        float ss = 0.f;
        #pragma unroll
        for(int ni=0;ni<4;ni++){ y[ni]=acc[mi][ni][r]; ss += y[ni]*y[ni]; }
        ss += __shfl_xor(ss,1,64); ss += __shfl_xor(ss,2,64);
        ss += __shfl_xor(ss,4,64); ss += __shfl_xor(ss,8,64);
        float nrm = rsqrtf(ss*(1.f/64.f) + 1e-6f);
        #pragma unroll
        for(int ni=0;ni<4;ni++) y[ni] *= nrm * wv[ni];
        u16* cp = (u16*)Cv + (size_t)row*N + ch;
        #pragma unroll
        for(int ni=0;ni<4;ni++){
          int d = (ni<<4)|q16;
          float rot = (ni<2) ? -y[ni+2] : y[ni-2];  // rotate_half pairing d^32
          float o = (y[ni]*cosT[l*64+d] + rot*sinT[l*64+d]) * qsc;
          cp[d] = f2bf(o);
        }
      }
    }
    return;
  }

  #pragma unroll
  for(int mi=0;mi<4;mi++){
    #pragma unroll
    for(int ni=0;ni<4;ni++){
      int row = rowbase + (wr<<6) + (mi<<4) + (g<<2);
      int col = colbase + (wc<<6) + (ni<<4) + q16;
      if(MODE==1){
        float* cp = (float*)Cv + (size_t)row*N + col;
        #pragma unroll
        for(int r=0;r<4;r++) cp[(size_t)r*N] = acc[mi][ni][r];
      } else {
        u16* cp = (u16*)Cv + (size_t)row*N + col;
        #pragma unroll
        for(int r=0;r<4;r++) cp[(size_t)r*N] = f2bf(acc[mi][ni][r]);
      }
    }
  }
}

// ---------------------------------------------------------------------------
// Flash attention, 32x32x16 MFMA. 4 waves x 64 q-rows (2 q-column-sets per
// wave) = 256 q/block @ 256 threads. Every K/V fragment read from LDS feeds
// 2x MFMAs (qsets A,B) -> LDS read traffic and bank conflicts halved vs the
// 8-wave/32q version (fattn was LDS-read-pipe bound). Sync structure, dbuf,
// swizzles (R15-validated) unchanged. accL ones-MFMA denominator, online max
// + defer (T13) per qset.
// ---------------------------------------------------------------------------
__global__ __launch_bounds__(256,2) void fattn(const u16* __restrict__ qkv, u16* __restrict__ Out){
  __shared__ __align__(16) u16 Ks0[128*64];     // 16KB [kv][e], slot^=(kv&7)
  __shared__ __align__(16) u16 Ks1[128*64];     // 16KB
  __shared__ __align__(16) u16 Vt[2][64*128];   // 2x16KB [d][kv], slot = chunk ^ f(d)

  int t = threadIdx.x, lane = t&63, w = t>>6;   // w in 0..3
  int ql = lane&31, h = lane>>5;
  int nwg = gridDim.x;
  int bid = (int)blockIdx.x;
  bid = (bid & 7)*(nwg>>3) + (bid>>3);          // XCD swizzle (nwg=512)
  int bh = bid >> 2, qt = bid & 3;              // 4 q-supertiles of 256 rows
  int b = bh >> 4, hd = bh & 15;
  const u16* base = qkv + (size_t)b*1024*3072;
  int Qb = (qt<<8) + (w<<6);                    // wave's 64 q-rows

  bv8 qfA[4], qfB[4];
  {
    const u16* qp = base + (size_t)(Qb+ql)*3072 + hd*64 + (h<<3);
    qfA[0] = *(const bv8*)(qp);
    qfA[1] = *(const bv8*)(qp+16);
    qfA[2] = *(const bv8*)(qp+32);
    qfA[3] = *(const bv8*)(qp+48);
    const u16* qp2 = qp + (size_t)32*3072;
    qfB[0] = *(const bv8*)(qp2);
    qfB[1] = *(const bv8*)(qp2+16);
    qfB[2] = *(const bv8*)(qp2+32);
    qfB[3] = *(const bv8*)(qp2+48);
  }
  bv8 onesb;
  #pragma unroll
  for(int j=0;j<8;j++) onesb[j] = (short)0x3F80;   // bf16 1.0

  f32x16 accO0A, accO1A, accO0B, accO1B, accLA, accLB;
  #pragma unroll
  for(int r=0;r<16;r++){ accO0A[r]=0.f; accO1A[r]=0.f; accO0B[r]=0.f; accO1B[r]=0.f; accLA[r]=0.f; accLB[r]=0.f; }
  float mA = -1e30f, mB = -1e30f;

  // V staging geometry (256 threads, R8/R11-validated)
  int d0v = (t&7)<<3;
  int c4  = t>>3;
  int sV = c4>>1, halfV = c4&1, kvr = c4<<2;
  int d15b = (t&1)<<3;
  int vxt  = ((t>>1)&3)<<1;                     // ((d>>4)&3)<<1 for d=(t&7)*8+i

  bv8 v0,v1,v2,v3;
  const u16* gV0 = base + (size_t)kvr*3072 + 2048 + hd*64 + d0v;

#define LDV(tl) { const u16* gV = gV0 + (size_t)(tl)*393216; \
    v0 = *(const bv8*)(gV);       v1 = *(const bv8*)(gV+3072); \
    v2 = *(const bv8*)(gV+6144);  v3 = *(const bv8*)(gV+9216); }

#define STV(buf) { \
    _Pragma("unroll") \
    for(int i=0;i<8;i++){ \
      int d = d0v + i; \
      u32x2 val; \
      val.x = (u32)(u16)v0[i] | ((u32)(u16)v1[i]<<16); \
      val.y = (u32)(u16)v2[i] | ((u32)(u16)v3[i]<<16); \
      *(u32x2*)((buf) + d*128 + ((((sV ^ (d15b+i) ^ vxt))<<3) + (halfV<<2))) = val; \
    } }

#define KDMA(tl, buf) { \
    _Pragma("unroll") \
    for(int i=0;i<4;i++){ \
      int si = ((w<<2)+i)*64 + lane; \
      int row = si>>3; \
      int esl = (si&7) ^ (row&7); \
      gl_lds16(base + (size_t)(((tl)<<7)+row)*3072 + 1024 + hd*64 + esl*8, (buf) + ((w<<2)+i)*512); \
    } }

// build PV A-frag pf (union {u32 u[4]; bv8 v;}) from P-regs SRC (f32x16), b0 in scope
#define MKPF(SRC, pfv) { \
      u32 Wlo0 = cvtpk_bf16(SRC[4*b0+0], SRC[4*b0+1]); \
      u32 Wlo1 = cvtpk_bf16(SRC[4*b0+2], SRC[4*b0+3]); \
      u32 Whi0 = cvtpk_bf16(SRC[4*b0+4], SRC[4*b0+5]); \
      u32 Whi1 = cvtpk_bf16(SRC[4*b0+6], SRC[4*b0+7]); \
      u32 X0 = h ? Wlo0 : Whi0; \
      u32 X1 = h ? Wlo1 : Whi1; \
      u32 x0 = (u32)__shfl_xor((int)X0, 32, 64); \
      u32 x1 = (u32)__shfl_xor((int)X1, 32, 64); \
      pfv.u[0] = h ? x0 : Wlo0; \
      pfv.u[1] = h ? x1 : Wlo1; \
      pfv.u[2] = h ? Whi0 : x0; \
      pfv.u[3] = h ? Whi1 : x1; }

// online softmax for one qset: rm/exp2 over S0_,S1_, rescale its accumulators
#define SOFTMAX(S0_, S1_, M_, AO0_, AO1_, AL_) { \
      float rm = -1e30f; \
      _Pragma("unroll") \
      for(int r=0;r<16;r++){ rm = fmaxf(rm, fmaxf(S0_[r], S1_[r])); } \
      rm = fmaxf(rm, __shfl_xor(rm, 32, 64)); \
      if(__any(rm > M_ + 8.0f)){ \
        float mnew = fmaxf(M_, rm); \
        float fac = exp2_fast(M_ - mnew); \
        M_ = mnew; \
        _Pragma("unroll") \
        for(int r=0;r<16;r++){ \
          int qs = (r&3) + ((r>>2)<<3) + (h<<2); \
          float fr = __shfl(fac, qs, 64); \
          AO0_[r] *= fr; AO1_[r] *= fr; AL_[r] *= fr; \
        } \
      } \
      _Pragma("unroll") \
      for(int r=0;r<16;r++){ \
        S0_[r] = exp2_fast(S0_[r]-M_); \
        S1_[r] = exp2_fast(S1_[r]-M_); \
      } }

  // prologue: K(0) DMA; V(0) -> Vt[0]; V(1) regs
  KDMA(0, (u16*)Ks0);
  LDV(0);
  STV(Vt[0]);
  LDV(1);

  int rx0 = (ql>>4)<<1;                         // read-side f(d) term for d=ql
  int dsw = ql & 15;

  for(int tile=0; tile<8; ++tile){
    u16* kcur = (tile&1) ? (u16*)Ks1 : (u16*)Ks0;
    u16* knxt = (tile&1) ? (u16*)Ks0 : (u16*)Ks1;
    u16* vcur = Vt[tile&1];
    u16* vnxt = Vt[(tile&1)^1];
    __syncthreads();                // buf(tile) ready; buf(tile+1) free to write
    if(tile<7) KDMA(tile+1, knxt);  // async DMA overlaps compute

    #pragma unroll
    for(int sub=0; sub<2; ++sub){
      f32x16 s0A, s1A, s0B, s1B;
      #pragma unroll
      for(int r=0;r<16;r++){ s0A[r]=0.f; s1A[r]=0.f; s0B[r]=0.f; s1B[r]=0.f; }
      int rowA = (sub<<6) + ql;
      int rowB = rowA + 32;
      __builtin_amdgcn_s_setprio(1);
      #pragma unroll
      for(int s=0;s<4;s++){
        bv8 ka = *(const bv8*)(kcur + rowA*64 + ((((s<<1)|h) ^ (rowA&7))<<3));
        bv8 kb = *(const bv8*)(kcur + rowB*64 + ((((s<<1)|h) ^ (rowB&7))<<3));
        s0A = MFMA32(ka, qfA[s], s0A);
        s1A = MFMA32(kb, qfA[s], s1A);
        s0B = MFMA32(ka, qfB[s], s0B);
        s1B = MFMA32(kb, qfB[s], s1B);
      }
      __builtin_amdgcn_s_setprio(0);

      if(sub==0){
        if(tile<7) STV(vnxt);       // V writes drain during softmax VALU phase
        if(tile<6) LDV(tile+2);     // prefetch V(tile+2) regs
      }

      SOFTMAX(s0A, s1A, mA, accO0A, accO1A, accLA);
      SOFTMAX(s0B, s1B, mB, accO0B, accO1B, accLB);

      #pragma unroll
      for(int tt=0; tt<4; ++tt){
        int b0 = (tt&1)<<1;
        union { u32 u[4]; bv8 v; } pfA, pfB;
        if(tt<2){ MKPF(s0A, pfA); MKPF(s0B, pfB); }
        else    { MKPF(s1A, pfA); MKPF(s1B, pfB); }
        int vslot0 = (((sub<<3)+(tt<<1)+h) ^ dsw ^ rx0);
        bv8 vf0 = *(const bv8*)(vcur + ql*128 + (vslot0<<3));
        bv8 vf1 = *(const bv8*)(vcur + (32+ql)*128 + ((vslot0^4)<<3));
        __builtin_amdgcn_s_setprio(1);
        accO0A = MFMA32(pfA.v, vf0, accO0A);
        accO1A = MFMA32(pfA.v, vf1, accO1A);
        accO0B = MFMA32(pfB.v, vf0, accO0B);
        accO1B = MFMA32(pfB.v, vf1, accO1B);
        accLA  = MFMA32(pfA.v, onesb, accLA);
        accLB  = MFMA32(pfB.v, onesb, accLB);
        __builtin_amdgcn_s_setprio(0);
      }
    }
  }
  // epilogue: lane-local divide per qset
  #pragma unroll
  for(int r=0;r<16;r++){
    int qs = (r&3) + ((r>>2)<<3) + (h<<2);
    float liA = rcp_fast(accLA[r]);
    float liB = rcp_fast(accLB[r]);
    size_t oA = (size_t)(b*1024 + Qb + qs)*1024 + hd*64 + ql;
    size_t oB = oA + (size_t)32*1024;
    Out[oA]      = f2bf(accO0A[r]*liA);
    Out[oA + 32] = f2bf(accO1A[r]*liA);
    Out[oB]      = f2bf(accO0B[r]*liB);
    Out[oB + 32] = f2bf(accO1B[r]*liB);
  }
#undef LDV
#undef STV
#undef KDMA
#undef MKPF
#undef SOFTMAX
}

extern "C" void kernel_launch(void* const* d_in, const int* in_sizes, int n_in,
                              void* d_out, int out_size, void* d_ws, size_t ws_size,
                              hipStream_t stream) {
  const float* x      = (const float*)d_in[0];
  const float* cosT   = (const float*)d_in[1];
  const float* sinT   = (const float*)d_in[2];
  const float* w_qkv  = (const float*)d_in[3];
  const float* w_proj = (const float*)d_in[4];
  const float* qw     = (const float*)d_in[5];
  const float* kw     = (const float*)d_in[6];
  float* out = (float*)d_out;

  // ws layout (u16 units): xb dead after qkv GEMM -> attn aliases it.
  u16* xb     = (u16*)d_ws;                         //  8388608 elems
  u16* wqkvb  = xb     + (size_t) 8388608;          //  3145728
  u16* wprojb = wqkvb  + (size_t) 3145728;          //  1048576
  u16* qkv    = wprojb + (size_t) 1048576;          // 25165824
  u16* attn   = xb;                                 //  8388608 (alias)

  cvt3<<<3072, 256, 0, stream>>>(x, w_qkv, w_proj, xb);

  gemm_bt<2><<<1536, 256, 0, stream>>>(xb, wqkvb, qkv, 8192, 3072, 1024,
                                       cosT, sinT, qw, kw);
  fattn   <<<512, 256, 0, stream>>>(qkv, attn);
  gemm_bt<1><<<512, 256, 0, stream>>>(attn, wprojb, out, 8192, 1024, 1024,
                                      nullptr, nullptr, nullptr, nullptr);
}

// Round 17
// 168.116 us; speedup vs baseline: 1.0926x; 1.0926x over previous
//
#include <hip/hip_runtime.h>
#include <hip/hip_bf16.h>
#include <stdint.h>

typedef uint16_t u16;
typedef uint32_t u32;
typedef __attribute__((ext_vector_type(8))) short bv8;    // 8 x bf16 (i16 bits), 4 VGPR
typedef __attribute__((ext_vector_type(4))) float f32x4;
typedef __attribute__((ext_vector_type(16))) float f32x16;
typedef __attribute__((ext_vector_type(2))) u32 u32x2;

#define MFMA(a,b,c)   __builtin_amdgcn_mfma_f32_16x16x32_bf16((a),(b),(c),0,0,0)
#define MFMA32(a,b,c) __builtin_amdgcn_mfma_f32_32x32x16_bf16((a),(b),(c),0,0,0)

__device__ __forceinline__ float bf2f(u16 v){ u32 x=(u32)v<<16; float f; __builtin_memcpy(&f,&x,4); return f; }
__device__ __forceinline__ u16 f2bf(float f){ u32 x; __builtin_memcpy(&x,&f,4); x += 0x7fffu + ((x>>16)&1u); return (u16)(x>>16); }
__device__ __forceinline__ u32 cvtpk_bf16(float lo, float hi){
  u32 r; asm("v_cvt_pk_bf16_f32 %0, %1, %2" : "=v"(r) : "v"(lo), "v"(hi)); return r;
}
__device__ __forceinline__ float exp2_fast(float x){
  float r; asm("v_exp_f32 %0, %1" : "=v"(r) : "v"(x)); return r;
}
__device__ __forceinline__ float rcp_fast(float x){
  float r; asm("v_rcp_f32 %0, %1" : "=v"(r) : "v"(x)); return r;
}

__device__ __forceinline__ void gl_lds16(const u16* g, u16* l){
  __builtin_amdgcn_global_load_lds((const __attribute__((address_space(1))) u32*)g,
                                   (__attribute__((address_space(3))) u32*)l, 16, 0, 0);
}

// fused fp32 -> bf16 convert of x / w_qkv / w_proj into contiguous ws region.
__global__ __launch_bounds__(256) void cvt3(const float* __restrict__ x, const float* __restrict__ wq,
                                            const float* __restrict__ wp, u16* __restrict__ dst){
  const long NA = 1048576, NB = 393216, NC = 131072;   // n8 per source
  long i = (long)blockIdx.x*256 + threadIdx.x;
  long stride = (long)gridDim.x*256;
  for(; i < NA+NB+NC; i += stride){
    const float* s;
    if(i < NA)            s = x  + i*8;
    else if(i < NA+NB)    s = wq + (i-NA)*8;
    else                  s = wp + (i-NA-NB)*8;
    f32x4 a = *(const f32x4*)(s);
    f32x4 b = *(const f32x4*)(s + 4);
    bv8 o;
    #pragma unroll
    for(int j=0;j<4;j++) o[j]   = (short)f2bf(a[j]);
    #pragma unroll
    for(int j=0;j<4;j++) o[4+j] = (short)f2bf(b[j]);
    *(bv8*)(dst + i*8) = o;
  }
}

// ---------------------------------------------------------------------------
// 8-phase 256x256 qkv GEMM (T2+T3+T4+T5), K=1024, BK=64, 8 waves (2Mx4N),
// wave tile 128x64. LDS: A,B as [2 buf][2 kh][256 row][32k] (64B rows),
// swizzle slot' = (k>>3) ^ ((row>>1)&3) -> conflict-free b128 reads; staged
// by global_load_lds with inverse-swizzled global source.
// Phase calendar (per K-tile t; barrier at each phase start; vmcnt(8) only
// at P0/P2 -> 4 newest half-tiles stay in flight):
//   P0(ks0,nh0): read A-ks0 + B-ks0-nh0 | stage A-kh1(t+1) | 16 MFMA
//   P1(ks0,nh1): read B-ks0-nh1 (A in regs) | stage B-kh1(t+1) | 16 MFMA
//   P2(ks1,nh0): read A-ks1 + B-ks1-nh0 | stage A-kh0(t+2) | 16 MFMA
//   P3(ks1,nh1): read B-ks1-nh1 | stage B-kh0(t+2) | 16 MFMA
// Region-lifetime audit: every stage target's last reader completed before
// the issuing phase's start barrier. Fused RMSNorm+RoPE epilogue on q/k cols.
// ---------------------------------------------------------------------------
__global__ __launch_bounds__(512,1) void gemm8p(const u16* __restrict__ A, const u16* __restrict__ B,
                                                u16* __restrict__ C,
                                                const float* __restrict__ cosT,
                                                const float* __restrict__ sinT,
                                                const float* __restrict__ qw,
                                                const float* __restrict__ kw){
  const int K = 1024, N = 3072;
  __shared__ __align__(16) u16 Ab[2][16384];    // [buf][kh*8192 + row*32 + k']
  __shared__ __align__(16) u16 Bb[2][16384];
  int nwg = gridDim.x;                          // 384
  int wg  = (int)blockIdx.x;
  wg = (wg & 7)*(nwg>>3) + (wg>>3);             // XCD swizzle (384 % 8 == 0)
  int tm = wg/12, tn = wg - tm*12;              // N/256 = 12
  int rowbase = tm<<8, colbase = tn<<8;
  int t = threadIdx.x, lane = t&63, w = t>>6;   // 8 waves
  int g = lane>>4, q16 = lane&15;
  int wm = w>>2, wn = w&3;

  f32x4 z = {0.f,0.f,0.f,0.f};
  f32x4 acc[8][4];
  #pragma unroll
  for(int i=0;i<8;i++)
    #pragma unroll
    for(int j=0;j<4;j++) acc[i][j]=z;

  // staging lane constants: instr (w,j) covers rows (w*2+j)*16 .. +16 of the half
  int srow = lane>>2;                           // row within 16-row group
  int sslotL = lane&3;                          // linear 16B slot within 64B row

#define STGA(tile, kh) { \
    _Pragma("unroll") \
    for(int j=0;j<2;j++){ \
      int row = (((w<<1)+j)<<4) + srow; \
      int s = sslotL ^ ((row>>1)&3); \
      gl_lds16(A + (size_t)(rowbase+row)*K + (tile)*64 + (kh)*32 + s*8, \
               Ab[(tile)&1] + (kh)*8192 + (((w<<1)+j)<<9)); \
    } }
#define STGB(tile, kh) { \
    _Pragma("unroll") \
    for(int j=0;j<2;j++){ \
      int row = (((w<<1)+j)<<4) + srow; \
      int s = sslotL ^ ((row>>1)&3); \
      gl_lds16(B + (size_t)(colbase+row)*K + (tile)*64 + (kh)*32 + s*8, \
               Bb[(tile)&1] + (kh)*8192 + (((w<<1)+j)<<9)); \
    } }

  // prologue: stage A0h0,B0h0,A0h1,B0h1,A1h0,B1h0 (12 issues/thread)
  STGA(0,0); STGB(0,0); STGA(0,1); STGB(0,1); STGA(1,0); STGB(1,0);

  bv8 af[8], bf[2];
#define RD_A(p_, ks_) { \
    _Pragma("unroll") \
    for(int mi=0;mi<8;mi++){ \
      int row = (wm<<7) + (mi<<4) + q16; \
      af[mi] = *(const bv8*)(Ab[p_] + (ks_)*8192 + row*32 + ((g ^ ((row>>1)&3))<<3)); \
    } }
#define RD_B(p_, ks_, nh_) { \
    _Pragma("unroll") \
    for(int ni=0;ni<2;ni++){ \
      int col = (wn<<6) + (nh_)*32 + (ni<<4) + q16; \
      bf[ni] = *(const bv8*)(Bb[p_] + (ks_)*8192 + col*32 + ((g ^ ((col>>1)&3))<<3)); \
    } }
#define DO_MFMA(nh_) { \
    __builtin_amdgcn_s_setprio(1); \
    _Pragma("unroll") \
    for(int mi=0;mi<8;mi++){ \
      acc[mi][(nh_)*2+0] = MFMA(af[mi], bf[0], acc[mi][(nh_)*2+0]); \
      acc[mi][(nh_)*2+1] = MFMA(af[mi], bf[1], acc[mi][(nh_)*2+1]); \
    } \
    __builtin_amdgcn_s_setprio(0); }

  for(int tl=0; tl<16; ++tl){
    int p = tl&1;
    // P0 (ks0, nh0)
    asm volatile("s_waitcnt vmcnt(8)" ::: "memory");
    asm volatile("s_barrier" ::: "memory");
    RD_A(p, 0); RD_B(p, 0, 0);
    if(tl<15) STGA(tl+1, 1);
    DO_MFMA(0);
    // P1 (ks0, nh1)
    asm volatile("s_barrier" ::: "memory");
    RD_B(p, 0, 1);
    if(tl<15) STGB(tl+1, 1);
    DO_MFMA(1);
    // P2 (ks1, nh0)
    asm volatile("s_waitcnt vmcnt(8)" ::: "memory");
    asm volatile("s_barrier" ::: "memory");
    RD_A(p, 1); RD_B(p, 1, 0);
    if(tl<14) STGA(tl+2, 0);
    DO_MFMA(0);
    // P3 (ks1, nh1)
    asm volatile("s_barrier" ::: "memory");
    RD_B(p, 1, 1);
    if(tl<14) STGB(tl+2, 0);
    DO_MFMA(1);
  }

  // epilogue: cols < 2048 -> fused RMSNorm + RoPE (+ q pre-scale); else plain
  if(colbase < 2048){
    int s = colbase>>10;                        // 0=q, 1=k
    const float* wsel = s ? kw : qw;
    int ch = colbase + (wn<<6);                 // this wave's head base
    float qsc = s ? 1.0f : 0.1803368801111437f; // 0.125*log2(e)
    float wv[4];
    #pragma unroll
    for(int ni=0;ni<4;ni++) wv[ni] = wsel[(ni<<4)|q16];
    #pragma unroll
    for(int mi=0;mi<8;mi++){
      #pragma unroll
      for(int r=0;r<4;r++){
        int row = rowbase + (wm<<7)+(mi<<4)+(g<<2)+r;
        int l = row & 1023;
        float y[4];
        float ss = 0.f;
        #pragma unroll
        for(int ni=0;ni<4;ni++){ y[ni]=acc[mi][ni][r]; ss += y[ni]*y[ni]; }
        ss += __shfl_xor(ss,1,64); ss += __shfl_xor(ss,2,64);
        ss += __shfl_xor(ss,4,64); ss += __shfl_xor(ss,8,64);
        float nrm = rsqrtf(ss*(1.f/64.f) + 1e-6f);
        #pragma unroll
        for(int ni=0;ni<4;ni++) y[ni] *= nrm * wv[ni];
        u16* cp = C + (size_t)row*N + ch;
        #pragma unroll
        for(int ni=0;ni<4;ni++){
          int d = (ni<<4)|q16;
          float rot = (ni<2) ? -y[ni+2] : y[ni-2];
          float o = (y[ni]*cosT[l*64+d] + rot*sinT[l*64+d]) * qsc;
          cp[d] = f2bf(o);
        }
      }
    }
  } else {
    #pragma unroll
    for(int mi=0;mi<8;mi++){
      #pragma unroll
      for(int ni=0;ni<4;ni++){
        int row = rowbase + (wm<<7) + (mi<<4) + (g<<2);
        int col = colbase + (wn<<6) + (ni<<4) + q16;
        u16* cp = C + (size_t)row*N + col;
        #pragma unroll
        for(int r=0;r<4;r++) cp[(size_t)r*N] = f2bf(acc[mi][ni][r]);
      }
    }
  }
#undef STGA
#undef STGB
#undef RD_A
#undef RD_B
#undef DO_MFMA
}

// ---------------------------------------------------------------------------
// 128x128 m97-structure GEMM (validated) — used for the proj GEMM (fp32 out).
// ---------------------------------------------------------------------------
__global__ __launch_bounds__(256,2) void gemm_bt(const u16* __restrict__ A, const u16* __restrict__ B,
                                                 float* __restrict__ C, int M, int N, int K){
  __shared__ __align__(16) u16 As[128*64];
  __shared__ __align__(16) u16 Bs[128*64];
  int nwg = gridDim.x;
  int wg  = (int)blockIdx.x;
  wg = (wg & 7)*(nwg>>3) + (wg>>3);          // XCD swizzle (nwg % 8 == 0)
  int nn = N>>7;
  int tm = wg/nn, tn = wg - tm*nn;
  int rowbase = tm<<7, colbase = tn<<7;
  int t = threadIdx.x, lane = t&63, w = t>>6;
  int g = lane>>4, q16 = lane&15;
  int wr = w>>1, wc = w&1;

  f32x4 z = {0.f,0.f,0.f,0.f};
  f32x4 acc[4][4];
  #pragma unroll
  for(int i=0;i<4;i++)
    #pragma unroll
    for(int j=0;j<4;j++) acc[i][j]=z;

  for(int k0=0;k0<K;k0+=64){
    __syncthreads();
    #pragma unroll
    for(int i=0;i<4;i++){
      int s = ((w<<2)+i)*64 + lane;
      int row = s>>3;
      int ksl = (s&7) ^ (row&7);
      gl_lds16(A + (size_t)(rowbase+row)*K + k0 + ksl*8, (u16*)As + ((w<<2)+i)*512);
      gl_lds16(B + (size_t)(colbase+row)*K + k0 + ksl*8, (u16*)Bs + ((w<<2)+i)*512);
    }
    __syncthreads();
    #pragma unroll
    for(int eks=0;eks<2;eks++){
      bv8 af[4], bfr[4];
      #pragma unroll
      for(int mi=0;mi<4;mi++){
        int row = (wr<<6)+(mi<<4)+q16;
        af[mi] = *(const bv8*)(As + row*64 + ((((eks<<2)|g) ^ (row&7))<<3));
      }
      #pragma unroll
      for(int ni=0;ni<4;ni++){
        int row = (wc<<6)+(ni<<4)+q16;
        bfr[ni] = *(const bv8*)(Bs + row*64 + ((((eks<<2)|g) ^ (row&7))<<3));
      }
      #pragma unroll
      for(int mi=0;mi<4;mi++)
        #pragma unroll
        for(int ni=0;ni<4;ni++)
          acc[mi][ni] = MFMA(af[mi], bfr[ni], acc[mi][ni]);
    }
  }
  #pragma unroll
  for(int mi=0;mi<4;mi++){
    #pragma unroll
    for(int ni=0;ni<4;ni++){
      int row = rowbase + (wr<<6) + (mi<<4) + (g<<2);
      int col = colbase + (wc<<6) + (ni<<4) + q16;
      float* cp = C + (size_t)row*N + col;
      #pragma unroll
      for(int r=0;r<4;r++) cp[(size_t)r*N] = acc[mi][ni][r];
    }
  }
}

// ---------------------------------------------------------------------------
// Flash attention (R15-validated, 62 us). 8 waves x 32 q-rows (BQ=256/block).
// Single barrier/tile; K+V double-buffered; Vt swizzle f(d)=(d&15)^(((d>>4)&3)<<1);
// STV-late; accL ones-MFMA denominator; online max + defer (T13).
// ---------------------------------------------------------------------------
__global__ __launch_bounds__(512,1) void fattn(const u16* __restrict__ qkv, u16* __restrict__ Out){
  __shared__ __align__(16) u16 Ks0[128*64];     // 16KB [kv][e], slot^=(kv&7)
  __shared__ __align__(16) u16 Ks1[128*64];     // 16KB
  __shared__ __align__(16) u16 Vt[2][64*128];   // 2x16KB [d][kv], slot = chunk ^ f(d)

  int t = threadIdx.x, lane = t&63, w = t>>6;   // w in 0..7
  int ql = lane&31, h = lane>>5;
  int nwg = gridDim.x;
  int bid = (int)blockIdx.x;
  bid = (bid & 7)*(nwg>>3) + (bid>>3);          // XCD swizzle (nwg=512)
  int bh = bid >> 2, qt = bid & 3;              // 4 q-supertiles of 256 rows
  int b = bh >> 4, hd = bh & 15;
  const u16* base = qkv + (size_t)b*1024*3072;
  int Qb = (qt<<8) + (w<<5);                    // wave's 32 q-rows

  bv8 qf[4];
  {
    const u16* qp = base + (size_t)(Qb+ql)*3072 + hd*64 + (h<<3);
    qf[0] = *(const bv8*)(qp);
    qf[1] = *(const bv8*)(qp+16);
    qf[2] = *(const bv8*)(qp+32);
    qf[3] = *(const bv8*)(qp+48);
  }
  bv8 onesb;
  #pragma unroll
  for(int j=0;j<8;j++) onesb[j] = (short)0x3F80;   // bf16 1.0

  f32x16 accO0, accO1, accL;
  #pragma unroll
  for(int r=0;r<16;r++){ accO0[r]=0.f; accO1[r]=0.f; accL[r]=0.f; }
  float m_run = -1e30f;

  // V staging geometry (threads 0..255, validated)
  bool vstage = (t < 256);
  int d0v = (t&7)<<3;
  int c4  = (t>>3)&31;
  int sV = c4>>1, halfV = c4&1, kvr = c4<<2;
  int d15b = (t&1)<<3;
  int vxt  = ((t>>1)&3)<<1;                     // ((d>>4)&3)<<1, d = (t&7)*8+i

  bv8 v0,v1,v2,v3;
  const u16* gV0 = base + (size_t)kvr*3072 + 2048 + hd*64 + d0v;

#define LDV(tl) if(vstage){ const u16* gV = gV0 + (size_t)(tl)*393216; \
    v0 = *(const bv8*)(gV);       v1 = *(const bv8*)(gV+3072); \
    v2 = *(const bv8*)(gV+6144);  v3 = *(const bv8*)(gV+9216); }

#define STV(buf) if(vstage){ \
    _Pragma("unroll") \
    for(int i=0;i<8;i++){ \
      int d = d0v + i; \
      u32x2 val; \
      val.x = (u32)(u16)v0[i] | ((u32)(u16)v1[i]<<16); \
      val.y = (u32)(u16)v2[i] | ((u32)(u16)v3[i]<<16); \
      *(u32x2*)((buf) + d*128 + ((((sV ^ (d15b+i) ^ vxt))<<3) + (halfV<<2))) = val; \
    } }

#define KDMA(tl, buf) { \
    _Pragma("unroll") \
    for(int i=0;i<2;i++){ \
      int si = ((w<<1)+i)*64 + lane; \
      int row = si>>3; \
      int esl = (si&7) ^ (row&7); \
      gl_lds16(base + (size_t)(((tl)<<7)+row)*3072 + 1024 + hd*64 + esl*8, (buf) + ((w<<1)+i)*512); \
    } }

  // prologue: K(0) DMA; V(0) -> Vt[0]; V(1) regs
  KDMA(0, (u16*)Ks0);
  LDV(0);
  STV(Vt[0]);
  LDV(1);

  int rx0 = (ql>>4)<<1;                         // read-side f(d) term for d=ql
  int dsw = ql & 15;

  for(int tile=0; tile<8; ++tile){
    u16* kcur = (tile&1) ? (u16*)Ks1 : (u16*)Ks0;
    u16* knxt = (tile&1) ? (u16*)Ks0 : (u16*)Ks1;
    u16* vcur = Vt[tile&1];
    u16* vnxt = Vt[(tile&1)^1];
    __syncthreads();                // buf(tile) ready; buf(tile+1) free to write
    if(tile<7) KDMA(tile+1, knxt);  // async DMA overlaps compute

    #pragma unroll
    for(int sub=0; sub<2; ++sub){
      f32x16 s0, s1;
      #pragma unroll
      for(int r=0;r<16;r++){ s0[r]=0.f; s1[r]=0.f; }
      int rowA = (sub<<6) + ql;
      int rowB = rowA + 32;
      __builtin_amdgcn_s_setprio(1);
      #pragma unroll
      for(int s=0;s<4;s++){
        bv8 ka = *(const bv8*)(kcur + rowA*64 + ((((s<<1)|h) ^ (rowA&7))<<3));
        bv8 kb = *(const bv8*)(kcur + rowB*64 + ((((s<<1)|h) ^ (rowB&7))<<3));
        s0 = MFMA32(ka, qf[s], s0);
        s1 = MFMA32(kb, qf[s], s1);
      }
      __builtin_amdgcn_s_setprio(0);

      if(sub==0){
        if(tile<7) STV(vnxt);       // V writes drain during softmax VALU phase
        if(tile<6) LDV(tile+2);     // prefetch V(tile+2) regs
      }

      float rm = -1e30f;
      #pragma unroll
      for(int r=0;r<16;r++){ rm = fmaxf(rm, fmaxf(s0[r], s1[r])); }
      rm = fmaxf(rm, __shfl_xor(rm, 32, 64));
      if(__any(rm > m_run + 8.0f)){         // defer-max (T13)
        float mnew = fmaxf(m_run, rm);
        float fac = exp2_fast(m_run - mnew);
        m_run = mnew;
        #pragma unroll
        for(int r=0;r<16;r++){
          int qs = (r&3) + ((r>>2)<<3) + (h<<2);
          float fr = __shfl(fac, qs, 64);
          accO0[r] *= fr; accO1[r] *= fr; accL[r] *= fr;
        }
      }
      #pragma unroll
      for(int r=0;r<16;r++){
        s0[r] = exp2_fast(s0[r]-m_run);
        s1[r] = exp2_fast(s1[r]-m_run);
      }

      #pragma unroll
      for(int tt=0; tt<4; ++tt){
        int b0 = (tt&1)<<1;
        float a0,a1,a2,a3,b4,b5,b6,b7;
        if(tt<2){ a0=s0[4*b0+0]; a1=s0[4*b0+1]; a2=s0[4*b0+2]; a3=s0[4*b0+3];
                  b4=s0[4*b0+4]; b5=s0[4*b0+5]; b6=s0[4*b0+6]; b7=s0[4*b0+7]; }
        else    { a0=s1[4*b0+0]; a1=s1[4*b0+1]; a2=s1[4*b0+2]; a3=s1[4*b0+3];
                  b4=s1[4*b0+4]; b5=s1[4*b0+5]; b6=s1[4*b0+6]; b7=s1[4*b0+7]; }
        u32 Wlo0 = cvtpk_bf16(a0,a1), Wlo1 = cvtpk_bf16(a2,a3);
        u32 Whi0 = cvtpk_bf16(b4,b5), Whi1 = cvtpk_bf16(b6,b7);
        u32 X0 = h ? Wlo0 : Whi0;
        u32 X1 = h ? Wlo1 : Whi1;
        u32 x0 = (u32)__shfl_xor((int)X0, 32, 64);
        u32 x1 = (u32)__shfl_xor((int)X1, 32, 64);
        union { u32 u[4]; bv8 v; } pf;
        pf.u[0] = h ? x0 : Wlo0;
        pf.u[1] = h ? x1 : Wlo1;
        pf.u[2] = h ? Whi0 : x0;
        pf.u[3] = h ? Whi1 : x1;
        int vslot0 = (((sub<<3)+(tt<<1)+h) ^ dsw ^ rx0);
        bv8 vf0 = *(const bv8*)(vcur + ql*128 + (vslot0<<3));
        bv8 vf1 = *(const bv8*)(vcur + (32+ql)*128 + ((vslot0^4)<<3));
        __builtin_amdgcn_s_setprio(1);
        accO0 = MFMA32(pf.v, vf0, accO0);
        accO1 = MFMA32(pf.v, vf1, accO1);
        accL  = MFMA32(pf.v, onesb, accL);   // denominator rowsum
        __builtin_amdgcn_s_setprio(0);
      }
    }
  }
  // epilogue: lane-local divide (accL[r] = rowsum for this r's q-row)
  #pragma unroll
  for(int r=0;r<16;r++){
    int qs = (r&3) + ((r>>2)<<3) + (h<<2);
    float li = rcp_fast(accL[r]);
    size_t o = (size_t)(b*1024 + Qb + qs)*1024 + hd*64 + ql;
    Out[o]      = f2bf(accO0[r]*li);
    Out[o + 32] = f2bf(accO1[r]*li);
  }
#undef LDV
#undef STV
#undef KDMA
}

extern "C" void kernel_launch(void* const* d_in, const int* in_sizes, int n_in,
                              void* d_out, int out_size, void* d_ws, size_t ws_size,
                              hipStream_t stream) {
  const float* x      = (const float*)d_in[0];
  const float* cosT   = (const float*)d_in[1];
  const float* sinT   = (const float*)d_in[2];
  const float* w_qkv  = (const float*)d_in[3];
  const float* w_proj = (const float*)d_in[4];
  const float* qw     = (const float*)d_in[5];
  const float* kw     = (const float*)d_in[6];
  float* out = (float*)d_out;

  // ws layout (u16 units): xb dead after qkv GEMM -> attn aliases it.
  u16* xb     = (u16*)d_ws;                         //  8388608 elems
  u16* wqkvb  = xb     + (size_t) 8388608;          //  3145728
  u16* wprojb = wqkvb  + (size_t) 3145728;          //  1048576
  u16* qkv    = wprojb + (size_t) 1048576;          // 25165824
  u16* attn   = xb;                                 //  8388608 (alias)

  cvt3<<<3072, 256, 0, stream>>>(x, w_qkv, w_proj, xb);

  gemm8p<<<384, 512, 0, stream>>>(xb, wqkvb, qkv, cosT, sinT, qw, kw);
  fattn <<<512, 512, 0, stream>>>(qkv, attn);
  gemm_bt<<<512, 256, 0, stream>>>(attn, wprojb, out, 8192, 1024, 1024);
}

// Round 18
// 163.263 us; speedup vs baseline: 1.1251x; 1.0297x over previous
//
#include <hip/hip_runtime.h>
#include <hip/hip_bf16.h>
#include <stdint.h>

typedef uint16_t u16;
typedef uint32_t u32;
typedef __attribute__((ext_vector_type(8))) short bv8;    // 8 x bf16 (i16 bits), 4 VGPR
typedef __attribute__((ext_vector_type(4))) float f32x4;
typedef __attribute__((ext_vector_type(16))) float f32x16;
typedef __attribute__((ext_vector_type(2))) u32 u32x2;

#define MFMA(a,b,c)   __builtin_amdgcn_mfma_f32_16x16x32_bf16((a),(b),(c),0,0,0)
#define MFMA32(a,b,c) __builtin_amdgcn_mfma_f32_32x32x16_bf16((a),(b),(c),0,0,0)

__device__ __forceinline__ float bf2f(u16 v){ u32 x=(u32)v<<16; float f; __builtin_memcpy(&f,&x,4); return f; }
__device__ __forceinline__ u16 f2bf(float f){ u32 x; __builtin_memcpy(&x,&f,4); x += 0x7fffu + ((x>>16)&1u); return (u16)(x>>16); }
__device__ __forceinline__ u32 cvtpk_bf16(float lo, float hi){
  u32 r; asm("v_cvt_pk_bf16_f32 %0, %1, %2" : "=v"(r) : "v"(lo), "v"(hi)); return r;
}
__device__ __forceinline__ float exp2_fast(float x){
  float r; asm("v_exp_f32 %0, %1" : "=v"(r) : "v"(x)); return r;
}
__device__ __forceinline__ float rcp_fast(float x){
  float r; asm("v_rcp_f32 %0, %1" : "=v"(r) : "v"(x)); return r;
}

__device__ __forceinline__ void gl_lds16(const u16* g, u16* l){
  __builtin_amdgcn_global_load_lds((const __attribute__((address_space(1))) u32*)g,
                                   (__attribute__((address_space(3))) u32*)l, 16, 0, 0);
}

// fused fp32 -> bf16 convert of x / w_qkv / w_proj into contiguous ws region.
__global__ __launch_bounds__(256) void cvt3(const float* __restrict__ x, const float* __restrict__ wq,
                                            const float* __restrict__ wp, u16* __restrict__ dst){
  const long NA = 1048576, NB = 393216, NC = 131072;   // n8 per source
  long i = (long)blockIdx.x*256 + threadIdx.x;
  long stride = (long)gridDim.x*256;
  for(; i < NA+NB+NC; i += stride){
    const float* s;
    if(i < NA)            s = x  + i*8;
    else if(i < NA+NB)    s = wq + (i-NA)*8;
    else                  s = wp + (i-NA-NB)*8;
    f32x4 a = *(const f32x4*)(s);
    f32x4 b = *(const f32x4*)(s + 4);
    bv8 o;
    #pragma unroll
    for(int j=0;j<4;j++) o[j]   = (short)f2bf(a[j]);
    #pragma unroll
    for(int j=0;j<4;j++) o[4+j] = (short)f2bf(b[j]);
    *(bv8*)(dst + i*8) = o;
  }
}

// ---------------------------------------------------------------------------
// C[m,n] = sum_k A[m,k] * B[n,k]   (A: MxK bf16 row-major, B: NxK bf16)
// 128x128 tile, BK=64, 4 waves. DOUBLE-BUFFERED LDS with single barrier per
// K-step (fattn-validated pattern): sync (drains stage(t) DMA; readers of the
// other buffer finished a barrier ago) -> stage(t+1) into other buf (DMA
// overlaps compute) -> compute(t). Removes the exposed-DMA-latency barrier.
// MODE 1: fp32 out. MODE 2: bf16 out + fused RMSNorm+RoPE on q/k cols.
// ---------------------------------------------------------------------------
template<int MODE>
__global__ __launch_bounds__(256,2) void gemm_bt(const u16* __restrict__ A, const u16* __restrict__ B,
                                                 void* __restrict__ Cv, int M, int N, int K,
                                                 const float* __restrict__ cosT,
                                                 const float* __restrict__ sinT,
                                                 const float* __restrict__ qw,
                                                 const float* __restrict__ kw){
  __shared__ __align__(16) u16 As[2][128*64];
  __shared__ __align__(16) u16 Bs[2][128*64];
  int nwg = gridDim.x;
  int wg  = (int)blockIdx.x;
  wg = (wg & 7)*(nwg>>3) + (wg>>3);          // XCD swizzle (nwg % 8 == 0)
  int nn = N>>7;
  int tm = wg/nn, tn = wg - tm*nn;
  int rowbase = tm<<7, colbase = tn<<7;
  int t = threadIdx.x, lane = t&63, w = t>>6;
  int g = lane>>4, q16 = lane&15;
  int wr = w>>1, wc = w&1;
  int nsteps = K>>6;

  f32x4 z = {0.f,0.f,0.f,0.f};
  f32x4 acc[4][4];
  #pragma unroll
  for(int i=0;i<4;i++)
    #pragma unroll
    for(int j=0;j<4;j++) acc[i][j]=z;

#define GSTAGE(step, p) { \
    _Pragma("unroll") \
    for(int i=0;i<4;i++){ \
      int s = ((w<<2)+i)*64 + lane; \
      int row = s>>3; \
      int ksl = (s&7) ^ (row&7); \
      gl_lds16(A + (size_t)(rowbase+row)*K + (step)*64 + ksl*8, (u16*)As[p] + ((w<<2)+i)*512); \
      gl_lds16(B + (size_t)(colbase+row)*K + (step)*64 + ksl*8, (u16*)Bs[p] + ((w<<2)+i)*512); \
    } }

  GSTAGE(0, 0);                              // prologue

  for(int st=0; st<nsteps; ++st){
    int p = st&1;
    __syncthreads();                         // stage(st) DMA drained; buf p^1 free
    if(st+1 < nsteps) GSTAGE(st+1, p^1);     // DMA overlaps this step's compute
    #pragma unroll
    for(int eks=0;eks<2;eks++){
      bv8 af[4], bfr[4];
      #pragma unroll
      for(int mi=0;mi<4;mi++){
        int row = (wr<<6)+(mi<<4)+q16;
        af[mi] = *(const bv8*)(As[p] + row*64 + ((((eks<<2)|g) ^ (row&7))<<3));
      }
      #pragma unroll
      for(int ni=0;ni<4;ni++){
        int row = (wc<<6)+(ni<<4)+q16;
        bfr[ni] = *(const bv8*)(Bs[p] + row*64 + ((((eks<<2)|g) ^ (row&7))<<3));
      }
      __builtin_amdgcn_s_setprio(1);
      #pragma unroll
      for(int mi=0;mi<4;mi++)
        #pragma unroll
        for(int ni=0;ni<4;ni++)
          acc[mi][ni] = MFMA(af[mi], bfr[ni], acc[mi][ni]);
      __builtin_amdgcn_s_setprio(0);
    }
  }
#undef GSTAGE

  if(MODE==2 && colbase < 2048){
    // fused RMSNorm + RoPE (+ q pre-scale 0.125*log2e) on this q/k head
    int s = colbase>>10;                       // 0=q, 1=k
    const float* wsel = s ? kw : qw;
    int ch = colbase + (wc<<6);
    float qsc = s ? 1.0f : 0.1803368801111437f;
    float wv[4];
    #pragma unroll
    for(int ni=0;ni<4;ni++) wv[ni] = wsel[(ni<<4)|q16];
    #pragma unroll
    for(int mi=0;mi<4;mi++){
      #pragma unroll
      for(int r=0;r<4;r++){
        int row = rowbase + (wr<<6)+(mi<<4)+(g<<2)+r;
        int l = row & 1023;
        float y[4];
        float ss = 0.f;
        #pragma unroll
        for(int ni=0;ni<4;ni++){ y[ni]=acc[mi][ni][r]; ss += y[ni]*y[ni]; }
        ss += __shfl_xor(ss,1,64); ss += __shfl_xor(ss,2,64);
        ss += __shfl_xor(ss,4,64); ss += __shfl_xor(ss,8,64);
        float nrm = rsqrtf(ss*(1.f/64.f) + 1e-6f);
        #pragma unroll
        for(int ni=0;ni<4;ni++) y[ni] *= nrm * wv[ni];
        u16* cp = (u16*)Cv + (size_t)row*N + ch;
        #pragma unroll
        for(int ni=0;ni<4;ni++){
          int d = (ni<<4)|q16;
          float rot = (ni<2) ? -y[ni+2] : y[ni-2];  // rotate_half pairing d^32
          float o = (y[ni]*cosT[l*64+d] + rot*sinT[l*64+d]) * qsc;
          cp[d] = f2bf(o);
        }
      }
    }
    return;
  }

  #pragma unroll
  for(int mi=0;mi<4;mi++){
    #pragma unroll
    for(int ni=0;ni<4;ni++){
      int row = rowbase + (wr<<6) + (mi<<4) + (g<<2);
      int col = colbase + (wc<<6) + (ni<<4) + q16;
      if(MODE==1){
        float* cp = (float*)Cv + (size_t)row*N + col;
        #pragma unroll
        for(int r=0;r<4;r++) cp[(size_t)r*N] = acc[mi][ni][r];
      } else {
        u16* cp = (u16*)Cv + (size_t)row*N + col;
        #pragma unroll
        for(int r=0;r<4;r++) cp[(size_t)r*N] = f2bf(acc[mi][ni][r]);
      }
    }
  }
}

// ---------------------------------------------------------------------------
// Flash attention (R15/R17-validated). 8 waves x 32 q-rows (BQ=256/block).
// Single barrier/tile; K+V double-buffered; Vt swizzle f(d)=(d&15)^(((d>>4)&3)<<1);
// STV-late; accL ones-MFMA denominator; online max + defer (T13).
// ---------------------------------------------------------------------------
__global__ __launch_bounds__(512,1) void fattn(const u16* __restrict__ qkv, u16* __restrict__ Out){
  __shared__ __align__(16) u16 Ks0[128*64];     // 16KB [kv][e], slot^=(kv&7)
  __shared__ __align__(16) u16 Ks1[128*64];     // 16KB
  __shared__ __align__(16) u16 Vt[2][64*128];   // 2x16KB [d][kv], slot = chunk ^ f(d)

  int t = threadIdx.x, lane = t&63, w = t>>6;   // w in 0..7
  int ql = lane&31, h = lane>>5;
  int nwg = gridDim.x;
  int bid = (int)blockIdx.x;
  bid = (bid & 7)*(nwg>>3) + (bid>>3);          // XCD swizzle (nwg=512)
  int bh = bid >> 2, qt = bid & 3;              // 4 q-supertiles of 256 rows
  int b = bh >> 4, hd = bh & 15;
  const u16* base = qkv + (size_t)b*1024*3072;
  int Qb = (qt<<8) + (w<<5);                    // wave's 32 q-rows

  bv8 qf[4];
  {
    const u16* qp = base + (size_t)(Qb+ql)*3072 + hd*64 + (h<<3);
    qf[0] = *(const bv8*)(qp);
    qf[1] = *(const bv8*)(qp+16);
    qf[2] = *(const bv8*)(qp+32);
    qf[3] = *(const bv8*)(qp+48);
  }
  bv8 onesb;
  #pragma unroll
  for(int j=0;j<8;j++) onesb[j] = (short)0x3F80;   // bf16 1.0

  f32x16 accO0, accO1, accL;
  #pragma unroll
  for(int r=0;r<16;r++){ accO0[r]=0.f; accO1[r]=0.f; accL[r]=0.f; }
  float m_run = -1e30f;

  // V staging geometry (threads 0..255, validated)
  bool vstage = (t < 256);
  int d0v = (t&7)<<3;
  int c4  = (t>>3)&31;
  int sV = c4>>1, halfV = c4&1, kvr = c4<<2;
  int d15b = (t&1)<<3;
  int vxt  = ((t>>1)&3)<<1;                     // ((d>>4)&3)<<1, d = (t&7)*8+i

  bv8 v0,v1,v2,v3;
  const u16* gV0 = base + (size_t)kvr*3072 + 2048 + hd*64 + d0v;

#define LDV(tl) if(vstage){ const u16* gV = gV0 + (size_t)(tl)*393216; \
    v0 = *(const bv8*)(gV);       v1 = *(const bv8*)(gV+3072); \
    v2 = *(const bv8*)(gV+6144);  v3 = *(const bv8*)(gV+9216); }

#define STV(buf) if(vstage){ \
    _Pragma("unroll") \
    for(int i=0;i<8;i++){ \
      int d = d0v + i; \
      u32x2 val; \
      val.x = (u32)(u16)v0[i] | ((u32)(u16)v1[i]<<16); \
      val.y = (u32)(u16)v2[i] | ((u32)(u16)v3[i]<<16); \
      *(u32x2*)((buf) + d*128 + ((((sV ^ (d15b+i) ^ vxt))<<3) + (halfV<<2))) = val; \
    } }

#define KDMA(tl, buf) { \
    _Pragma("unroll") \
    for(int i=0;i<2;i++){ \
      int si = ((w<<1)+i)*64 + lane; \
      int row = si>>3; \
      int esl = (si&7) ^ (row&7); \
      gl_lds16(base + (size_t)(((tl)<<7)+row)*3072 + 1024 + hd*64 + esl*8, (buf) + ((w<<1)+i)*512); \
    } }

  // prologue: K(0) DMA; V(0) -> Vt[0]; V(1) regs
  KDMA(0, (u16*)Ks0);
  LDV(0);
  STV(Vt[0]);
  LDV(1);

  int rx0 = (ql>>4)<<1;                         // read-side f(d) term for d=ql
  int dsw = ql & 15;

  for(int tile=0; tile<8; ++tile){
    u16* kcur = (tile&1) ? (u16*)Ks1 : (u16*)Ks0;
    u16* knxt = (tile&1) ? (u16*)Ks0 : (u16*)Ks1;
    u16* vcur = Vt[tile&1];
    u16* vnxt = Vt[(tile&1)^1];
    __syncthreads();                // buf(tile) ready; buf(tile+1) free to write
    if(tile<7) KDMA(tile+1, knxt);  // async DMA overlaps compute

    #pragma unroll
    for(int sub=0; sub<2; ++sub){
      f32x16 s0, s1;
      #pragma unroll
      for(int r=0;r<16;r++){ s0[r]=0.f; s1[r]=0.f; }
      int rowA = (sub<<6) + ql;
      int rowB = rowA + 32;
      __builtin_amdgcn_s_setprio(1);
      #pragma unroll
      for(int s=0;s<4;s++){
        bv8 ka = *(const bv8*)(kcur + rowA*64 + ((((s<<1)|h) ^ (rowA&7))<<3));
        bv8 kb = *(const bv8*)(kcur + rowB*64 + ((((s<<1)|h) ^ (rowB&7))<<3));
        s0 = MFMA32(ka, qf[s], s0);
        s1 = MFMA32(kb, qf[s], s1);
      }
      __builtin_amdgcn_s_setprio(0);

      if(sub==0){
        if(tile<7) STV(vnxt);       // V writes drain during softmax VALU phase
        if(tile<6) LDV(tile+2);     // prefetch V(tile+2) regs
      }

      float rm = -1e30f;
      #pragma unroll
      for(int r=0;r<16;r++){ rm = fmaxf(rm, fmaxf(s0[r], s1[r])); }
      rm = fmaxf(rm, __shfl_xor(rm, 32, 64));
      if(__any(rm > m_run + 8.0f)){         // defer-max (T13)
        float mnew = fmaxf(m_run, rm);
        float fac = exp2_fast(m_run - mnew);
        m_run = mnew;
        #pragma unroll
        for(int r=0;r<16;r++){
          int qs = (r&3) + ((r>>2)<<3) + (h<<2);
          float fr = __shfl(fac, qs, 64);
          accO0[r] *= fr; accO1[r] *= fr; accL[r] *= fr;
        }
      }
      #pragma unroll
      for(int r=0;r<16;r++){
        s0[r] = exp2_fast(s0[r]-m_run);
        s1[r] = exp2_fast(s1[r]-m_run);
      }

      #pragma unroll
      for(int tt=0; tt<4; ++tt){
        int b0 = (tt&1)<<1;
        float a0,a1,a2,a3,b4,b5,b6,b7;
        if(tt<2){ a0=s0[4*b0+0]; a1=s0[4*b0+1]; a2=s0[4*b0+2]; a3=s0[4*b0+3];
                  b4=s0[4*b0+4]; b5=s0[4*b0+5]; b6=s0[4*b0+6]; b7=s0[4*b0+7]; }
        else    { a0=s1[4*b0+0]; a1=s1[4*b0+1]; a2=s1[4*b0+2]; a3=s1[4*b0+3];
                  b4=s1[4*b0+4]; b5=s1[4*b0+5]; b6=s1[4*b0+6]; b7=s1[4*b0+7]; }
        u32 Wlo0 = cvtpk_bf16(a0,a1), Wlo1 = cvtpk_bf16(a2,a3);
        u32 Whi0 = cvtpk_bf16(b4,b5), Whi1 = cvtpk_bf16(b6,b7);
        u32 X0 = h ? Wlo0 : Whi0;
        u32 X1 = h ? Wlo1 : Whi1;
        u32 x0 = (u32)__shfl_xor((int)X0, 32, 64);
        u32 x1 = (u32)__shfl_xor((int)X1, 32, 64);
        union { u32 u[4]; bv8 v; } pf;
        pf.u[0] = h ? x0 : Wlo0;
        pf.u[1] = h ? x1 : Wlo1;
        pf.u[2] = h ? Whi0 : x0;
        pf.u[3] = h ? Whi1 : x1;
        int vslot0 = (((sub<<3)+(tt<<1)+h) ^ dsw ^ rx0);
        bv8 vf0 = *(const bv8*)(vcur + ql*128 + (vslot0<<3));
        bv8 vf1 = *(const bv8*)(vcur + (32+ql)*128 + ((vslot0^4)<<3));
        __builtin_amdgcn_s_setprio(1);
        accO0 = MFMA32(pf.v, vf0, accO0);
        accO1 = MFMA32(pf.v, vf1, accO1);
        accL  = MFMA32(pf.v, onesb, accL);   // denominator rowsum
        __builtin_amdgcn_s_setprio(0);
      }
    }
  }
  // epilogue: lane-local divide (accL[r] = rowsum for this r's q-row)
  #pragma unroll
  for(int r=0;r<16;r++){
    int qs = (r&3) + ((r>>2)<<3) + (h<<2);
    float li = rcp_fast(accL[r]);
    size_t o = (size_t)(b*1024 + Qb + qs)*1024 + hd*64 + ql;
    Out[o]      = f2bf(accO0[r]*li);
    Out[o + 32] = f2bf(accO1[r]*li);
  }
#undef LDV
#undef STV
#undef KDMA
}

extern "C" void kernel_launch(void* const* d_in, const int* in_sizes, int n_in,
                              void* d_out, int out_size, void* d_ws, size_t ws_size,
                              hipStream_t stream) {
  const float* x      = (const float*)d_in[0];
  const float* cosT   = (const float*)d_in[1];
  const float* sinT   = (const float*)d_in[2];
  const float* w_qkv  = (const float*)d_in[3];
  const float* w_proj = (const float*)d_in[4];
  const float* qw     = (const float*)d_in[5];
  const float* kw     = (const float*)d_in[6];
  float* out = (float*)d_out;

  // ws layout (u16 units): xb dead after qkv GEMM -> attn aliases it.
  u16* xb     = (u16*)d_ws;                         //  8388608 elems
  u16* wqkvb  = xb     + (size_t) 8388608;          //  3145728
  u16* wprojb = wqkvb  + (size_t) 3145728;          //  1048576
  u16* qkv    = wprojb + (size_t) 1048576;          // 25165824
  u16* attn   = xb;                                 //  8388608 (alias)

  cvt3<<<3072, 256, 0, stream>>>(x, w_qkv, w_proj, xb);

  gemm_bt<2><<<1536, 256, 0, stream>>>(xb, wqkvb, qkv, 8192, 3072, 1024,
                                       cosT, sinT, qw, kw);
  fattn  <<<512, 512, 0, stream>>>(qkv, attn);
  gemm_bt<1><<<512, 256, 0, stream>>>(attn, wprojb, out, 8192, 1024, 1024,
                                      nullptr, nullptr, nullptr, nullptr);
}